// Round 3
// baseline (4337.407 us; speedup 1.0000x reference)
//
#include <hip/hip_runtime.h>
#include <math.h>

#define N_ROWS 32768
#define DIM    1024
#define NE     64
#define KTOP   8

// v4 = v2's design with the fatal 4-byte bug fixed.
// v2 failed: 65536 B smem + 4 B isLast = 65540 B static LDS > 64 KB cap.
// v3 failed: acc[8][8] runtime-ish indexing (ra/rb/xbase[c1]) -> scratch spill
//            (WRITE_SIZE 711 MB, VALUBusy 14%). Reverted entirely.
//
// Structure (v0-proven): lane = row, acc[64] (AGPR-resident, proven by v0's
// VGPR=52 + zero scratch traffic), wave wid owns k in [128*wid, 128*wid+128).
// Fix for v0's bottleneck (w via s_load -> serialized scalar-K$ misses,
// VALUBusy 23%): stage per-kb w chunk [64e][8wid][16k] (32 KB) into LDS via
// global_load_lds (dest = wave-uniform base + lane*16B, the exact HW pattern),
// double-buffered 2x32 KB; compute reads are broadcast ds_read_b128
// (same-address across lanes -> conflict-free, data delivered once/wave).
// Per-kb: issue next chunk -> compute 1024 FMA/lane -> barrier (drains vmcnt).
// isLast lives in the last 4 B of buf1: only written after all buf1 reads.

typedef const __attribute__((address_space(1))) void gas_t;
typedef __attribute__((address_space(3))) void las_t;

__device__ __forceinline__ void gload_lds16(const float* g, float* l) {
    __builtin_amdgcn_global_load_lds((gas_t*)g, (las_t*)l, 16, 0, 0);
}

extern "C" __global__ void __launch_bounds__(512, 4)
moe_gate_kernel(const float* __restrict__ x, const float* __restrict__ gw,
                const float* __restrict__ nw, const float* __restrict__ noise,
                float* __restrict__ out0, float* __restrict__ out1,
                float* __restrict__ lossp,
                double* __restrict__ esum, int* __restrict__ ticket) {
    // 16384 floats = 65536 B exactly (the static cap).
    // Main loop: w double-buffer [2][8192] floats.
    // Epilogue overlay: red = floats 0..4615 (inside buf0),
    //                   lg  = floats 4616..8774 (tail crosses into buf1;
    //                         written only after the post-kb7 barrier).
    // isLast = int at float slot 16383 (buf1's last word; written post-epilogue).
    __shared__ __align__(16) float smem[16384];
    float* wlds = smem;
    float* red  = smem;            // [8*577]
    float* lg   = smem + 4616;     // [64*65]
#define IS_LAST (*(int*)(smem + 16383))

    const int tid   = threadIdx.x;
    const int lane  = tid & 63;
    const int wid   = __builtin_amdgcn_readfirstlane(tid >> 6);   // 0..7
    const int row0  = blockIdx.x * 64;
    const int kbase = wid * 128;                                  // wave k-range

    float acc[NE];
#pragma unroll
    for (int e = 0; e < NE; ++e) acc[e] = 0.f;

    const float* xr = x + (size_t)(row0 + lane) * DIM + kbase;    // per-lane VMEM

    // Staging map (per thread, 4 calls x 16 B): LDS float = c*2048 + tid*4 + q
    // holds gw[e][w8*128 + kb*16 + j], e = c*16 + (tid>>5), w8 = (tid>>2)&7,
    // j = (tid&3)*4 + q  ->  LDS layout [e][w8][j] = e*128 + w8*16 + j.
    // Wave-uniform LDS base + lane*16B: matches global_load_lds HW semantics.
    const float* gWb = gw + (size_t)(tid >> 5) * DIM + ((tid >> 2) & 7) * 128 + (tid & 3) * 4;
    float* lW = wlds + tid * 4;                  // + buf*8192 + c*2048

    float xv[16], xn[16];
#pragma unroll
    for (int i = 0; i < 4; ++i) *(float4*)(xv + 4 * i) = *(const float4*)(xr + 4 * i);

    // prologue: stage kb=0 into buf0; __syncthreads drains vmcnt(0) first.
#pragma unroll
    for (int c = 0; c < 4; ++c) gload_lds16(gWb + c * 16 * DIM, lW + c * 2048);
    __syncthreads();

#pragma unroll 1
    for (int kb = 0; kb < 8; ++kb) {
        const int buf = kb & 1;
        if (kb < 7) {
            // issue next chunk into buf^1 NOW -- lands during the FMA phase.
            float* ld = lW + (buf ^ 1) * 8192;
#pragma unroll
            for (int c = 0; c < 4; ++c)
                gload_lds16(gWb + c * 16 * DIM + (kb + 1) * 16, ld + c * 2048);
            const float* xp = xr + (kb + 1) * 16;
#pragma unroll
            for (int i = 0; i < 4; ++i) *(float4*)(xn + 4 * i) = *(const float4*)(xp + 4 * i);
        }

        // compute: 256 broadcast ds_read_b128 + 1024 FMA/lane from wlds[buf]
        const float* wb = wlds + buf * 8192 + wid * 16;
#pragma unroll
        for (int e = 0; e < NE; ++e) {
            const float4 a0 = *(const float4*)(wb + e * 128 + 0);
            const float4 a1 = *(const float4*)(wb + e * 128 + 4);
            const float4 a2 = *(const float4*)(wb + e * 128 + 8);
            const float4 a3 = *(const float4*)(wb + e * 128 + 12);
            float s = acc[e];
            s = fmaf(a0.x, xv[0], s);  s = fmaf(a0.y, xv[1], s);
            s = fmaf(a0.z, xv[2], s);  s = fmaf(a0.w, xv[3], s);
            s = fmaf(a1.x, xv[4], s);  s = fmaf(a1.y, xv[5], s);
            s = fmaf(a1.z, xv[6], s);  s = fmaf(a1.w, xv[7], s);
            s = fmaf(a2.x, xv[8], s);  s = fmaf(a2.y, xv[9], s);
            s = fmaf(a2.z, xv[10], s); s = fmaf(a2.w, xv[11], s);
            s = fmaf(a3.x, xv[12], s); s = fmaf(a3.y, xv[13], s);
            s = fmaf(a3.z, xv[14], s); s = fmaf(a3.w, xv[15], s);
            acc[e] = s;
        }

        if (kb < 7) {
#pragma unroll
            for (int i = 0; i < 16; ++i) xv[i] = xn[i];
            __syncthreads();           // drains vmcnt -> buf^1 staged for all waves
        }
    }

    // ---- k-split reduction: sum acc over the 8 waves, transpose into lg ----
    // red writes hit buf0 while laggard waves still read buf1 (kb=7): disjoint.
#pragma unroll
    for (int ec = 0; ec < 8; ++ec) {
#pragma unroll
        for (int j = 0; j < 8; ++j) red[wid * 577 + lane * 9 + j] = acc[ec * 8 + j];
        __syncthreads();
        {
            const int r = tid & 63, j = tid >> 6;
            float s = 0.f;
#pragma unroll
            for (int w = 0; w < 8; ++w) s += red[w * 577 + r * 9 + j];
            lg[r * 65 + ec * 8 + j] = s;
        }
        __syncthreads();
    }

    // ---- epilogue: wave handles 8 rows, lane = expert (v0-proven code) ----
    const float nwl = nw[lane];
    float epart = 0.f;

#pragma unroll 1
    for (int i = 0; i < 8; ++i) {
        const int    lrow = wid * 8 + i;
        const size_t grow = (size_t)(row0 + lrow);
        const float  lgv  = lg[lrow * 65 + lane];

        // dense softmax over 64 experts (load-balance mean term)
        float m = lgv;
#pragma unroll
        for (int off = 32; off; off >>= 1) m = fmaxf(m, __shfl_xor(m, off));
        float p = __expf(lgv - m);
        float s = p;
#pragma unroll
        for (int off = 32; off; off >>= 1) s += __shfl_xor(s, off);
        epart += p / s;

        // noisy logits + iterative top-8 argmax (tie -> lower index)
        const float nz    = noise[grow * NE + lane];
        const float noisy = fmaf(nz, nwl, lgv);
        float cur  = noisy;
        bool  sel  = false;
        float mtop = 0.f;
        int   myid = 0;
#pragma unroll
        for (int j = 0; j < KTOP; ++j) {
            float v = cur; int id = lane;
#pragma unroll
            for (int off = 32; off; off >>= 1) {
                float ov = __shfl_xor(v, off);
                int   oi = __shfl_xor(id, off);
                if (ov > v || (ov == v && oi < id)) { v = ov; id = oi; }
            }
            if (j == 0) mtop = v;
            if (lane == id) { sel = true; cur = -INFINITY; }
            if (lane == j) myid = id;
        }

        float swv  = sel ? __expf(noisy - mtop) : 0.f;
        float ssum = swv;
#pragma unroll
        for (int off = 32; off; off >>= 1) ssum += __shfl_xor(ssum, off);

        out0[grow * NE + lane] = swv / ssum;                // coalesced 256 B/row
        if (lane < KTOP) out1[grow * KTOP + lane] = (float)myid;
    }

    // ---- load-balance sums: block partial -> device atomics ----
    __syncthreads();                   // lg reads done; reuse red
    red[wid * 64 + lane] = epart;
    __syncthreads();
    if (tid < NE) {
        float t = 0.f;
#pragma unroll
        for (int w = 0; w < 8; ++w) t += red[w * 64 + tid];
        atomicAdd(&esum[tid], (double)t);
        __threadfence();
    }
    __syncthreads();
    if (tid == 0) {
        int t = atomicAdd(ticket, 1);
        IS_LAST = (t == (int)gridDim.x - 1);   // buf1 reads all done long ago
        __threadfence();
    }
    __syncthreads();

    // ---- last block computes the scalar loss (f64) ----
    if (IS_LAST && tid < NE) {
        double v = atomicAdd(&esum[tid], 0.0);    // device-scope read
        double mean = v * (1.0 / 32768.0);
        double d  = mean - (1.0 / 64.0);
        double sq = d * d;
#pragma unroll
        for (int off = 32; off; off >>= 1) sq += __shfl_xor(sq, off);
        if (tid == 0) lossp[0] = (float)(sq * (1.0 / 64.0) * 0.01);
    }
#undef IS_LAST
}

extern "C" void kernel_launch(void* const* d_in, const int* in_sizes, int n_in,
                              void* d_out, int out_size, void* d_ws, size_t ws_size,
                              hipStream_t stream) {
    const float* x     = (const float*)d_in[0];   // [32768,1024]
    const float* gw    = (const float*)d_in[1];   // [64,1024]
    const float* nw    = (const float*)d_in[2];   // [64]
    const float* noise = (const float*)d_in[3];   // [32768,64]

    float* out0  = (float*)d_out;                       // [32768,64] gated weights
    float* out1  = out0 + (size_t)N_ROWS * NE;          // [32768,8] ids as f32
    float* lossp = out1 + (size_t)N_ROWS * KTOP;        // scalar loss

    double* esum   = (double*)d_ws;                     // [64]
    int*    ticket = (int*)((char*)d_ws + 512);

    hipMemsetAsync(d_ws, 0, 520, stream);
    moe_gate_kernel<<<N_ROWS / 64, 512, 0, stream>>>(x, gw, nw, noise,
                                                     out0, out1, lossp, esum, ticket);
}

// Round 4
// 293.747 us; speedup vs baseline: 14.7658x; 14.7658x over previous
//
#include <hip/hip_runtime.h>
#include <math.h>

#define N_ROWS 32768
#define DIM    1024
#define NE     64
#define KTOP   8

// v5: spill-proof 8x8 register-tiled GEMM front-end, barrier-free main loop.
//
// History: v0 (222us) w via s_load -> scalar-K$ latency-bound (VALUBusy 23%).
// v3 (390us) 8x8 tile but derived acc indices (ra/rb/xbase[c1]) -> scratch
// spill (WRITE 711MB). v4 (4230us) broadcast-LDS w: unrolled 64-expert loop
// hoisted load results -> acc[64] spilled (WRITE 8.7GB); broadcast also costs
// 4B/FMA on the LDS return bus (4x FMA time) - wrong design even without spill.
//
// v5 accounting (per CU): FMA floor 65K cyc. LDS return bus 128B/cyc forces
// <=1B per lane-FMA => 8x8 tile: lane (er,rr) owns rows rr*8+[0,8) x experts
// er*8+[0,8); per k reads 8 x + 8 w floats (4x ds_read_b128) for 64 FMAs.
// Spill-proofing: acc/xf/wf indexed ONLY by fully-unrolled m/n; k-step loop
// is unroll-1 so one iteration's 16 load-results live at a time (~90 VGPR);
// no prefetch regs - 8 waves/SIMD TLP hides VMEM+DS latency.
// Wave wid stages AND consumes only k = rc*64 + wid*8 + q (its own 2KB LDS
// slices) -> zero barriers in the main loop; DS ops are in-order per wave.
// Bank patterns: stage writes = 64 consecutive words (2-way, free); reads =
// 256B contiguous row chunks (2-way on (rr,rr+4) pairs, ~free).
// k-split across waves -> v3's verified reduction; v0's verified epilogue.

extern "C" __global__ void __launch_bounds__(512, 4)
moe_gate_kernel(const float* __restrict__ x, const float* __restrict__ gw,
                const float* __restrict__ nw, const float* __restrict__ noise,
                float* __restrict__ out0, float* __restrict__ out1,
                float* __restrict__ lossp,
                double* __restrict__ esum, int* __restrict__ ticket) {
    __shared__ __align__(16) float smem[8448];   // 33,792 B -> 4 blocks/CU
    __shared__ int isLast;
    float* xt  = smem;          // [64k][64r] x tile; wave wid owns rows wid*8..+8
    float* wt  = smem + 4096;   // [64k][64e] w tile; same ownership
    float* red = smem;          // overlay: k-split reduction scratch [4096]
    float* lg  = smem + 4096;   // overlay: logits [64*65]

    const int tid  = threadIdx.x;
    const int lane = tid & 63;
    const int wid  = __builtin_amdgcn_readfirstlane(tid >> 6);   // 0..7
    const int er   = lane >> 3;       // expert-group
    const int rr   = lane & 7;        // row-group
    const int er8  = er * 8;
    const int rr8  = rr * 8;
    const int row0 = blockIdx.x * 64;

    float acc[8][8];
#pragma unroll
    for (int m = 0; m < 8; ++m)
#pragma unroll
        for (int n = 0; n < 8; ++n) acc[m][n] = 0.f;

    // Staging: thread (wid,lane) loads x[row0+lane][rc*64+wid*8 .. +8] and
    // gw[lane][rc*64+wid*8 .. +8]; writes k-major xt[k][lane] / wt[k][lane].
    const float* gx  = x  + (size_t)(row0 + lane) * DIM + wid * 8;
    const float* gwp = gw + (size_t)lane * DIM + wid * 8;
    float*       xw  = xt + wid * 512 + lane;   // + q*64
    float*       ww  = wt + wid * 512 + lane;
    const float* xr  = xt + wid * 512 + rr8;    // + q*64
    const float* wr  = wt + wid * 512 + er8;

#pragma unroll 1
    for (int rc = 0; rc < 16; ++rc) {
        float px[8], pw[8];
        *(float4*)(px + 0) = *(const float4*)(gx  + rc * 64 + 0);
        *(float4*)(px + 4) = *(const float4*)(gx  + rc * 64 + 4);
        *(float4*)(pw + 0) = *(const float4*)(gwp + rc * 64 + 0);
        *(float4*)(pw + 4) = *(const float4*)(gwp + rc * 64 + 4);
#pragma unroll
        for (int q = 0; q < 8; ++q) {      // 2-way banks: free
            xw[q * 64] = px[q];
            ww[q * 64] = pw[q];
        }
        // px/pw dead here -> no overlap with xf/wf (bounds VGPR pressure).
#pragma unroll 1
        for (int q = 0; q < 8; ++q) {      // k = rc*64 + wid*8 + q
            float xf[8], wf[8];
            *(float4*)(xf + 0) = *(const float4*)(xr + q * 64 + 0);
            *(float4*)(xf + 4) = *(const float4*)(xr + q * 64 + 4);
            *(float4*)(wf + 0) = *(const float4*)(wr + q * 64 + 0);
            *(float4*)(wf + 4) = *(const float4*)(wr + q * 64 + 4);
#pragma unroll
            for (int m = 0; m < 8; ++m)
#pragma unroll
                for (int n = 0; n < 8; ++n)
                    acc[m][n] = fmaf(xf[m], wf[n], acc[m][n]);
        }
    }

    // ---- k-split reduction over the 8 waves (v3-verified, verbatim) ----
    __syncthreads();                  // all waves done with xt/wt
#pragma unroll
    for (int s = 0; s < 8; ++s) {     // row = rr*8 + s
        float4 v0 = make_float4(acc[s][0], acc[s][1], acc[s][2], acc[s][3]);
        float4 v1 = make_float4(acc[s][4], acc[s][5], acc[s][6], acc[s][7]);
        *(float4*)(red + wid * 512 + rr * 64 + er8 + 0) = v0;
        *(float4*)(red + wid * 512 + rr * 64 + er8 + 4) = v1;
        __syncthreads();
        {
            const int r2 = tid >> 6, e = tid & 63;
            float t = 0.f;
#pragma unroll
            for (int w = 0; w < 8; ++w) t += red[w * 512 + r2 * 64 + e];
            lg[(r2 * 8 + s) * 65 + e] = t;   // row r2*8+s, expert e
        }
        __syncthreads();
    }

    // ---- epilogue: wave handles 8 rows, lane = expert (v0-proven code) ----
    const float nwl = nw[lane];
    float epart = 0.f;

#pragma unroll 1
    for (int i = 0; i < 8; ++i) {
        const int    lrow = wid * 8 + i;
        const size_t grow = (size_t)(row0 + lrow);
        const float  lgv  = lg[lrow * 65 + lane];

        // dense softmax over 64 experts (load-balance mean term)
        float m = lgv;
#pragma unroll
        for (int off = 32; off; off >>= 1) m = fmaxf(m, __shfl_xor(m, off));
        float p = __expf(lgv - m);
        float s = p;
#pragma unroll
        for (int off = 32; off; off >>= 1) s += __shfl_xor(s, off);
        epart += p / s;

        // noisy logits + iterative top-8 argmax (tie -> lower index)
        const float nz    = noise[grow * NE + lane];
        const float noisy = fmaf(nz, nwl, lgv);
        float cur  = noisy;
        bool  sel  = false;
        float mtop = 0.f;
        int   myid = 0;
#pragma unroll
        for (int j = 0; j < KTOP; ++j) {
            float v = cur; int id = lane;
#pragma unroll
            for (int off = 32; off; off >>= 1) {
                float ov = __shfl_xor(v, off);
                int   oi = __shfl_xor(id, off);
                if (ov > v || (ov == v && oi < id)) { v = ov; id = oi; }
            }
            if (j == 0) mtop = v;
            if (lane == id) { sel = true; cur = -INFINITY; }
            if (lane == j) myid = id;
        }

        float swv  = sel ? __expf(noisy - mtop) : 0.f;
        float ssum = swv;
#pragma unroll
        for (int off = 32; off; off >>= 1) ssum += __shfl_xor(ssum, off);

        out0[grow * NE + lane] = swv / ssum;                // coalesced 256 B/row
        if (lane < KTOP) out1[grow * KTOP + lane] = (float)myid;
    }

    // ---- load-balance sums: block partial -> device atomics ----
    __syncthreads();                   // lg reads done; reuse red
    red[wid * 64 + lane] = epart;
    __syncthreads();
    if (tid < NE) {
        float t = 0.f;
#pragma unroll
        for (int w = 0; w < 8; ++w) t += red[w * 64 + tid];
        atomicAdd(&esum[tid], (double)t);
        __threadfence();
    }
    __syncthreads();
    if (tid == 0) {
        int t = atomicAdd(ticket, 1);
        isLast = (t == (int)gridDim.x - 1);
        __threadfence();
    }
    __syncthreads();

    // ---- last block computes the scalar loss (f64) ----
    if (isLast && tid < NE) {
        double v = atomicAdd(&esum[tid], 0.0);    // device-scope read
        double mean = v * (1.0 / 32768.0);
        double d  = mean - (1.0 / 64.0);
        double sq = d * d;
#pragma unroll
        for (int off = 32; off; off >>= 1) sq += __shfl_xor(sq, off);
        if (tid == 0) lossp[0] = (float)(sq * (1.0 / 64.0) * 0.01);
    }
}

extern "C" void kernel_launch(void* const* d_in, const int* in_sizes, int n_in,
                              void* d_out, int out_size, void* d_ws, size_t ws_size,
                              hipStream_t stream) {
    const float* x     = (const float*)d_in[0];   // [32768,1024]
    const float* gw    = (const float*)d_in[1];   // [64,1024]
    const float* nw    = (const float*)d_in[2];   // [64]
    const float* noise = (const float*)d_in[3];   // [32768,64]

    float* out0  = (float*)d_out;                       // [32768,64] gated weights
    float* out1  = out0 + (size_t)N_ROWS * NE;          // [32768,8] ids as f32
    float* lossp = out1 + (size_t)N_ROWS * KTOP;        // scalar loss

    double* esum   = (double*)d_ws;                     // [64]
    int*    ticket = (int*)((char*)d_ws + 512);

    hipMemsetAsync(d_ws, 0, 520, stream);
    moe_gate_kernel<<<N_ROWS / 64, 512, 0, stream>>>(x, gw, nw, noise,
                                                     out0, out1, lossp, esum, ticket);
}